// Round 1
// baseline (1739.212 us; speedup 1.0000x reference)
//
#include <hip/hip_runtime.h>
#include <hip/hip_cooperative_groups.h>
#include <math.h>

namespace cg = cooperative_groups;

typedef __attribute__((ext_vector_type(4))) float f32x4;
typedef __attribute__((ext_vector_type(8))) short s16x8;

constexpr int B = 32, T = 48, H = 256, E = 128, TD = 48;
constexpr int OUT = 40000, NOUTC = 40048, NPADC = 40064;
constexpr int G3 = 768, DIN = 176;

__device__ __forceinline__ float sigmoidf_(float x){ return 1.f/(1.f+__expf(-x)); }
__device__ __forceinline__ unsigned short f2bf(float f){
  unsigned int u = __float_as_uint(f);
  u += 0x7fffu + ((u>>16)&1u);   // RNE
  return (unsigned short)(u>>16);
}
__device__ __forceinline__ void gl_lds16(const unsigned short* g, unsigned short* l){
  __builtin_amdgcn_global_load_lds((const __attribute__((address_space(1))) void*)g,
                                   (__attribute__((address_space(3))) void*)l, 16, 0, 0);
}

// ---------------- transpose w_ih0[:, :128] -> wT[e][g] for coalesced K1 loads --------
__global__ void wt_kernel(const float* __restrict__ w_ih0, float* __restrict__ wT){
  int i = blockIdx.x*256 + threadIdx.x;       // over 128*768
  if (i >= E*G3) return;
  int e = i / G3, g = i % G3;
  wT[i] = w_ih0[g*DIN + e];
}

// ---------------- K1: xp0[t*B+b][g] = emb(loc)·w_ih0[g,:128] + w_ih0[g,128+time] + b_ih0[g]
__global__ void xp0_kernel(const int* __restrict__ locations, const int* __restrict__ times,
                           const float* __restrict__ embed, const float* __restrict__ wT,
                           const float* __restrict__ w_ih0, const float* __restrict__ b_ih0,
                           float* __restrict__ xp0)
{
  __shared__ float emb_s[16][E];
  __shared__ int tm_s[16];
  const int r0 = blockIdx.x * 16;
  const int tid = threadIdx.x;
  for (int i = tid; i < 16*E; i += 256) {
    int p = i >> 7, e = i & 127;
    int r = r0 + p; int t = r >> 5, b = r & 31;
    emb_s[p][e] = embed[(size_t)locations[b*T + t]*E + e];
  }
  if (tid < 16) {
    int r = r0 + tid; int t = r >> 5, b = r & 31;
    tm_s[tid] = times[b*T + t];
  }
  __syncthreads();
  const int g = tid;  // gate rows g, g+256, g+512
  float acc[16][3];
  #pragma unroll
  for (int p=0;p<16;p++){acc[p][0]=0.f;acc[p][1]=0.f;acc[p][2]=0.f;}
  for (int e = 0; e < E; e += 4) {
    float w0_[4], w1_[4], w2_[4];
    #pragma unroll
    for (int i=0;i<4;i++){
      w0_[i]=wT[(e+i)*G3 + g];
      w1_[i]=wT[(e+i)*G3 + 256 + g];
      w2_[i]=wT[(e+i)*G3 + 512 + g];
    }
    #pragma unroll
    for (int p=0;p<16;p++){
      float4 ev = *(const float4*)&emb_s[p][e];
      acc[p][0] += ev.x*w0_[0]+ev.y*w0_[1]+ev.z*w0_[2]+ev.w*w0_[3];
      acc[p][1] += ev.x*w1_[0]+ev.y*w1_[1]+ev.z*w1_[2]+ev.w*w1_[3];
      acc[p][2] += ev.x*w2_[0]+ev.y*w2_[1]+ev.z*w2_[2]+ev.w*w2_[3];
    }
  }
  #pragma unroll
  for (int p=0;p<16;p++){
    int r = r0+p; int tt = tm_s[p];
    xp0[(size_t)r*G3 + g]       = acc[p][0] + b_ih0[g]     + w_ih0[g*DIN       + E + tt];
    xp0[(size_t)r*G3 + 256 + g] = acc[p][1] + b_ih0[g+256] + w_ih0[(g+256)*DIN + E + tt];
    xp0[(size_t)r*G3 + 512 + g] = acc[p][2] + b_ih0[g+512] + w_ih0[(g+512)*DIN + E + tt];
  }
}

// ---------------- K2: cooperative 2-layer GRU, pipelined (L0 step t || L1 step t-1) ----
struct GruArgs {
  const float* xp0; const float* traj; const int* labels;
  const float* w_hh0; const float* b_hh0;
  const float* w_ih1; const float* b_ih1; const float* w_hh1; const float* b_hh1;
  float* h0buf; float* h1buf; float* y0buf; float* y1;
};

__global__ void gru_kernel(GruArgs a)
{
  // strides 257 / 255: (b*257+k)%32=(b+k)%32, (b*255+k)%32=(k-b)%32 -> conflict-free
  __shared__ float s0[32*257];   // 32896 B
  __shared__ float s1[32*255];   // 32640 B  (total exactly 64 KiB)
  cg::grid_group grid = cg::this_grid();
  const int blk = blockIdx.x, tid = threadIdx.x;
  const bool isL1 = blk >= 32;
  const int ib = isL1 ? blk - 32 : blk;
  const int jj = tid >> 5;        // 0..7
  const int b  = tid & 31;
  const int j  = ib*8 + jj;       // 0..255

  // init hidden state from traj_table via torch-view semantics
  {
    int bb = ib, h = tid;  // 32 blocks/layer × 256 threads = full [32][256]
    float v = a.traj[(size_t)a.labels[(isL1?16:0) + (bb>>1)]*512 + (bb&1)*256 + h];
    (isL1 ? a.h1buf : a.h0buf)[bb*256 + h] = v;
  }
  grid.sync();

  for (int p = 0; p <= T; ++p) {
    if (!isL1) {
      if (p < T) {
        const int t = p, cur = p & 1;
        const float* hsrc = a.h0buf + cur*8192;
        for (int i = tid; i < 8192; i += 256)
          s0[(i>>8)*257 + (i&255)] = hsrc[i];
        __syncthreads();
        float hr=0.f,hz=0.f,hn=0.f;
        const float* wr = a.w_hh0 + j*H;
        const float* wz = a.w_hh0 + (j+256)*H;
        const float* wn = a.w_hh0 + (j+512)*H;
        const float* hrow = s0 + b*257;
        for (int k = 0; k < H; k += 4) {
          float h0v=hrow[k], h1v=hrow[k+1], h2v=hrow[k+2], h3v=hrow[k+3];
          float4 wr4 = *(const float4*)(wr+k);
          float4 wz4 = *(const float4*)(wz+k);
          float4 wn4 = *(const float4*)(wn+k);
          hr += h0v*wr4.x + h1v*wr4.y + h2v*wr4.z + h3v*wr4.w;
          hz += h0v*wz4.x + h1v*wz4.y + h2v*wz4.z + h3v*wz4.w;
          hn += h0v*wn4.x + h1v*wn4.y + h2v*wn4.z + h3v*wn4.w;
        }
        const size_t rbase = (size_t)(t*B + b)*G3;
        float xr = a.xp0[rbase + j], xz = a.xp0[rbase + 256 + j], xn = a.xp0[rbase + 512 + j];
        float r = sigmoidf_(xr + hr + a.b_hh0[j]);
        float z = sigmoidf_(xz + hz + a.b_hh0[256+j]);
        float n = tanhf(xn + r*(hn + a.b_hh0[512+j]));
        float hnew = (1.f - z)*n + z*hrow[j];
        a.h0buf[((p+1)&1)*8192 + b*256 + j] = hnew;
        a.y0buf[cur*8192 + b*256 + j] = hnew;
      }
    } else {
      if (p >= 1) {
        const int t = p-1, cur = t & 1;
        const float* xsrc = a.y0buf + cur*8192;
        const float* hsrc = a.h1buf + cur*8192;
        for (int i = tid; i < 8192; i += 256) {
          int bb = i>>8, k = i&255;
          s0[bb*257+k] = xsrc[i];
          s1[bb*255+k] = hsrc[i];
        }
        __syncthreads();
        float xr=0.f,xz=0.f,xn=0.f,hr=0.f,hz=0.f,hn=0.f;
        const float* xrow = s0 + b*257;
        const float* hrow = s1 + b*255;
        const float* wxr = a.w_ih1 + j*H;
        const float* wxz = a.w_ih1 + (j+256)*H;
        const float* wxn = a.w_ih1 + (j+512)*H;
        const float* whr = a.w_hh1 + j*H;
        const float* whz = a.w_hh1 + (j+256)*H;
        const float* whn = a.w_hh1 + (j+512)*H;
        for (int k = 0; k < H; k += 4) {
          float x0=xrow[k], x1=xrow[k+1], x2=xrow[k+2], x3=xrow[k+3];
          float h0v=hrow[k], h1v=hrow[k+1], h2v=hrow[k+2], h3v=hrow[k+3];
          float4 a4 = *(const float4*)(wxr+k);
          float4 b4 = *(const float4*)(wxz+k);
          float4 c4 = *(const float4*)(wxn+k);
          float4 d4 = *(const float4*)(whr+k);
          float4 e4 = *(const float4*)(whz+k);
          float4 f4 = *(const float4*)(whn+k);
          xr += x0*a4.x + x1*a4.y + x2*a4.z + x3*a4.w;
          xz += x0*b4.x + x1*b4.y + x2*b4.z + x3*b4.w;
          xn += x0*c4.x + x1*c4.y + x2*c4.z + x3*c4.w;
          hr += h0v*d4.x + h1v*d4.y + h2v*d4.z + h3v*d4.w;
          hz += h0v*e4.x + h1v*e4.y + h2v*e4.z + h3v*e4.w;
          hn += h0v*f4.x + h1v*f4.y + h2v*f4.z + h3v*f4.w;
        }
        float r = sigmoidf_(xr + a.b_ih1[j]     + hr + a.b_hh1[j]);
        float z = sigmoidf_(xz + a.b_ih1[256+j] + hz + a.b_hh1[256+j]);
        float n = tanhf(xn + a.b_ih1[512+j] + r*(hn + a.b_hh1[512+j]));
        float hnew = (1.f - z)*n + z*hrow[j];
        a.h1buf[((t+1)&1)*8192 + b*256 + j] = hnew;
        a.y1[(size_t)(t*B + b)*H + j] = hnew;
      }
    }
    grid.sync();
  }
}

// ---------------- casts to bf16 -----------------------------------------------------
__global__ void castw_kernel(const float* __restrict__ fcw, unsigned short* __restrict__ wbf){
  int g = blockIdx.x*256 + threadIdx.x;   // float4 groups, NPADC*64 total
  if (g >= NPADC*64) return;
  int row = g >> 6;
  ushort4 o;
  if (row < NOUTC) {
    float4 v = ((const float4*)fcw)[g];
    o.x=f2bf(v.x); o.y=f2bf(v.y); o.z=f2bf(v.z); o.w=f2bf(v.w);
  } else { o.x=0; o.y=0; o.z=0; o.w=0; }
  ((ushort4*)wbf)[g] = o;
}

__global__ void casta_kernel(const float* __restrict__ y1, unsigned short* __restrict__ abf){
  int g = blockIdx.x*256 + threadIdx.x;   // float4 groups over 1536*256/4
  if (g >= B*T*H/4) return;
  int m = g >> 6;               // dst row = b*48+t
  int kg = (g & 63) * 4;
  int bb = m / T, t = m % T;
  float4 v = *(const float4*)(y1 + ((size_t)(t*B + bb)*H + kg));
  ushort4 o;
  o.x=f2bf(fmaxf(v.x,0.f)); o.y=f2bf(fmaxf(v.y,0.f));
  o.z=f2bf(fmaxf(v.z,0.f)); o.w=f2bf(fmaxf(v.w,0.f));
  ((ushort4*)abf)[g] = o;
}

// ---------------- K4: bf16 MFMA GEMM  C[1536 x 40048] = A·W^T + b -> raw logits ------
__global__ void __launch_bounds__(256) gemm_kernel(const unsigned short* __restrict__ Abf,
                                                   const unsigned short* __restrict__ Wbf,
                                                   const float* __restrict__ fc_b,
                                                   float* __restrict__ dout)
{
  __shared__ unsigned short As[128*32];
  __shared__ unsigned short Ws[128*32];
  const int m0 = blockIdx.x * 128;
  const int n0 = blockIdx.y * 128;
  const int tid = threadIdx.x;
  const int lane = tid & 63;
  const int wv = tid >> 6;
  f32x4 acc[2][8];
  #pragma unroll
  for (int i=0;i<2;i++)
    #pragma unroll
    for(int jx=0;jx<8;jx++) acc[i][jx] = (f32x4){0.f,0.f,0.f,0.f};

  const int srow = tid >> 2;
  const int skoff = (tid & 3) * 8;
  const unsigned short* aptr = Abf + (size_t)(m0 + srow)*256 + skoff;
  const unsigned short* wptr = Wbf + (size_t)(n0 + srow)*256 + skoff;
  unsigned short* asd = &As[tid*8];
  unsigned short* wsd = &Ws[tid*8];

  const int fr = lane & 15;
  const int fk = (lane >> 4) * 8;

  for (int kk = 0; kk < 256; kk += 32) {
    gl_lds16(aptr + kk,            asd);
    gl_lds16(aptr + 64*256 + kk,   asd + 64*32);
    gl_lds16(wptr + kk,            wsd);
    gl_lds16(wptr + 64*256 + kk,   wsd + 64*32);
    __syncthreads();
    s16x8 a0 = *(const s16x8*)&As[(wv*32 + fr)*32 + fk];
    s16x8 a1 = *(const s16x8*)&As[(wv*32 + 16 + fr)*32 + fk];
    #pragma unroll
    for (int ct = 0; ct < 8; ++ct) {
      s16x8 bfr = *(const s16x8*)&Ws[(ct*16 + fr)*32 + fk];
      acc[0][ct] = __builtin_amdgcn_mfma_f32_16x16x32_bf16(a0, bfr, acc[0][ct], 0, 0, 0);
      acc[1][ct] = __builtin_amdgcn_mfma_f32_16x16x32_bf16(a1, bfr, acc[1][ct], 0, 0, 0);
    }
    __syncthreads();
  }

  const int quad = lane >> 4;
  #pragma unroll
  for (int rt = 0; rt < 2; ++rt) {
    #pragma unroll
    for (int ct = 0; ct < 8; ++ct) {
      int col = n0 + ct*16 + fr;
      if (col < NOUTC) {
        float bias = fc_b[col];
        #pragma unroll
        for (int i = 0; i < 4; ++i) {
          int row = m0 + wv*32 + rt*16 + quad*4 + i;
          float v = acc[rt][ct][i] + bias;
          if (col < OUT) dout[(size_t)row*OUT + col] = v;
          else dout[(size_t)OUT*B*T + (size_t)row*TD + (col - OUT)] = v;
        }
      }
    }
  }
}

// ---------------- K5: per-row online logsumexp over the 40000 loc logits -------------
__global__ void stats_kernel(const float* __restrict__ dout, float* __restrict__ logz){
  const int r = blockIdx.x;
  const float4* row = (const float4*)(dout + (size_t)r*OUT);
  float m = -INFINITY, s = 0.f;
  for (int i = threadIdx.x; i < OUT/4; i += 256) {
    float4 v = row[i];
    float mx = fmaxf(fmaxf(v.x,v.y), fmaxf(v.z,v.w));
    if (mx > m) { s *= __expf(m - mx); m = mx; }
    s += __expf(v.x-m)+__expf(v.y-m)+__expf(v.z-m)+__expf(v.w-m);
  }
  #pragma unroll
  for (int off = 1; off < 64; off <<= 1) {
    float m2 = __shfl_xor(m, off);
    float s2 = __shfl_xor(s, off);
    float nm = fmaxf(m, m2);
    s = s*__expf(m-nm) + s2*__expf(m2-nm);
    m = nm;
  }
  __shared__ float sm[4], ss[4];
  if ((threadIdx.x & 63) == 0){ sm[threadIdx.x>>6]=m; ss[threadIdx.x>>6]=s; }
  __syncthreads();
  if (threadIdx.x == 0){
    float M=sm[0], S=ss[0];
    #pragma unroll
    for (int w=1;w<4;w++){
      float nm=fmaxf(M,sm[w]); S = S*__expf(M-nm)+ss[w]*__expf(sm[w]-nm); M=nm;
    }
    logz[r] = M + logf(S);
  }
}

// ---------------- K6: in-place normalize loc ----------------------------------------
__global__ void norm_kernel(float* __restrict__ dout, const float* __restrict__ logz){
  size_t i = (size_t)blockIdx.x*256 + threadIdx.x;   // float4 index
  if (i >= (size_t)B*T*OUT/4) return;
  int r = (int)(i / (OUT/4));
  float lz = logz[r];
  float4* p = (float4*)dout + i;
  float4 v = *p;
  v.x -= lz; v.y -= lz; v.z -= lz; v.w -= lz;
  *p = v;
}

// ---------------- K7: tm log_softmax (48 wide), in place -----------------------------
__global__ void tm_kernel(float* __restrict__ dout){
  const int r = blockIdx.x;
  const int lane = threadIdx.x;   // 64
  float* base = dout + (size_t)OUT*B*T + (size_t)r*TD;
  float v = (lane < TD) ? base[lane] : -INFINITY;
  float m = v;
  #pragma unroll
  for (int off=32; off; off>>=1) m = fmaxf(m, __shfl_xor(m, off));
  float e = (lane < TD) ? __expf(v - m) : 0.f;
  float s = e;
  #pragma unroll
  for (int off=32; off; off>>=1) s += __shfl_xor(s, off);
  float lz = m + logf(s);
  if (lane < TD) base[lane] = v - lz;
}

extern "C" void kernel_launch(void* const* d_in, const int* in_sizes, int n_in,
                              void* d_out, int out_size, void* d_ws, size_t ws_size,
                              hipStream_t stream)
{
  const int*   locations = (const int*)d_in[0];
  const int*   times     = (const int*)d_in[1];
  const int*   labels    = (const int*)d_in[2];
  const float* embed     = (const float*)d_in[3];
  const float* traj      = (const float*)d_in[4];
  const float* fc_w      = (const float*)d_in[5];
  const float* fc_b      = (const float*)d_in[6];
  const float* w_ih0     = (const float*)d_in[7];
  const float* w_hh0     = (const float*)d_in[8];
  const float* b_ih0     = (const float*)d_in[9];
  const float* b_hh0     = (const float*)d_in[10];
  const float* w_ih1     = (const float*)d_in[11];
  const float* w_hh1     = (const float*)d_in[12];
  const float* b_ih1     = (const float*)d_in[13];
  const float* b_hh1     = (const float*)d_in[14];
  float* out = (float*)d_out;
  char* ws = (char*)d_ws;

  float* xp0            = (float*)(ws);                    // 4,718,592 B
  float* h0buf          = (float*)(ws + 4718592);          //    65,536
  float* h1buf          = (float*)(ws + 4784128);          //    65,536
  float* y0buf          = (float*)(ws + 4849664);          //    65,536
  float* y1             = (float*)(ws + 4915200);          // 1,572,864
  float* logz           = (float*)(ws + 6488064);          //     6,144
  unsigned short* abf   = (unsigned short*)(ws + 6494208); //   786,432
  unsigned short* wbf   = (unsigned short*)(ws + 7280640); // 20,512,768
  float* wT             = (float*)(ws + 27793408);         //   393,216  -> total ~28.2 MB

  castw_kernel<<<dim3((NPADC*64 + 255)/256), dim3(256), 0, stream>>>(fc_w, wbf);
  wt_kernel<<<dim3((E*G3 + 255)/256), dim3(256), 0, stream>>>(w_ih0, wT);
  xp0_kernel<<<dim3(96), dim3(256), 0, stream>>>(locations, times, embed, wT, w_ih0, b_ih0, xp0);

  GruArgs ga{xp0, traj, labels, w_hh0, b_hh0, w_ih1, b_ih1, w_hh1, b_hh1,
             h0buf, h1buf, y0buf, y1};
  void* kargs[] = { &ga };
  hipLaunchCooperativeKernel((void*)gru_kernel, dim3(64), dim3(256), kargs, 0, stream);

  casta_kernel<<<dim3((B*T*H/4 + 255)/256), dim3(256), 0, stream>>>(y1, abf);
  gemm_kernel<<<dim3(12, 313), dim3(256), 0, stream>>>(abf, wbf, fc_b, out);
  stats_kernel<<<dim3(B*T), dim3(256), 0, stream>>>(out, logz);
  norm_kernel<<<dim3((B*T*OUT/4 + 255)/256), dim3(256), 0, stream>>>(out, logz);
  tm_kernel<<<dim3(B*T), dim3(64), 0, stream>>>(out);
}

// Round 2
// 895.457 us; speedup vs baseline: 1.9423x; 1.9423x over previous
//
#include <hip/hip_runtime.h>
#include <hip/hip_cooperative_groups.h>
#include <math.h>

namespace cg = cooperative_groups;

typedef __attribute__((ext_vector_type(4))) float f32x4;
typedef __attribute__((ext_vector_type(8))) short s16x8;

constexpr int B = 32, T = 48, H = 256, E = 128, TD = 48;
constexpr int OUT = 40000, NOUTC = 40048, NPADC = 40064;
constexpr int G3 = 768, DIN = 176;

__device__ __forceinline__ float sigmoidf_(float x){ return 1.f/(1.f+__expf(-x)); }
__device__ __forceinline__ float tanhf_(float x){
  float e = __expf(2.f*x);            // inf-safe: x>>0 -> 1, x<<0 -> -1
  return 1.f - 2.f/(e + 1.f);
}
__device__ __forceinline__ unsigned short f2bf(float f){
  unsigned int u = __float_as_uint(f);
  u += 0x7fffu + ((u>>16)&1u);   // RNE
  return (unsigned short)(u>>16);
}
__device__ __forceinline__ s16x8 pack8(float4 u, float4 v){
  s16x8 r;
  r[0]=(short)f2bf(u.x); r[1]=(short)f2bf(u.y); r[2]=(short)f2bf(u.z); r[3]=(short)f2bf(u.w);
  r[4]=(short)f2bf(v.x); r[5]=(short)f2bf(v.y); r[6]=(short)f2bf(v.z); r[7]=(short)f2bf(v.w);
  return r;
}
__device__ __forceinline__ void gl_lds16(const unsigned short* g, unsigned short* l){
  __builtin_amdgcn_global_load_lds((const __attribute__((address_space(1))) void*)g,
                                   (__attribute__((address_space(3))) void*)l, 16, 0, 0);
}

// ---------------- transpose w_ih0[:, :128] -> wT[e][g] for coalesced K1 loads --------
__global__ void wt_kernel(const float* __restrict__ w_ih0, float* __restrict__ wT){
  int i = blockIdx.x*256 + threadIdx.x;       // over 128*768
  if (i >= E*G3) return;
  int e = i / G3, g = i % G3;
  wT[i] = w_ih0[g*DIN + e];
}

// ---------------- K1: xp0[t*B+b][g] = emb(loc)·w_ih0[g,:128] + w_ih0[g,128+time] + b_ih0[g]
__global__ void xp0_kernel(const int* __restrict__ locations, const int* __restrict__ times,
                           const float* __restrict__ embed, const float* __restrict__ wT,
                           const float* __restrict__ w_ih0, const float* __restrict__ b_ih0,
                           float* __restrict__ xp0)
{
  __shared__ float emb_s[16][E];
  __shared__ int tm_s[16];
  const int r0 = blockIdx.x * 16;
  const int tid = threadIdx.x;
  for (int i = tid; i < 16*E; i += 256) {
    int p = i >> 7, e = i & 127;
    int r = r0 + p; int t = r >> 5, b = r & 31;
    emb_s[p][e] = embed[(size_t)locations[b*T + t]*E + e];
  }
  if (tid < 16) {
    int r = r0 + tid; int t = r >> 5, b = r & 31;
    tm_s[tid] = times[b*T + t];
  }
  __syncthreads();
  const int g = tid;  // gate rows g, g+256, g+512
  float acc[16][3];
  #pragma unroll
  for (int p=0;p<16;p++){acc[p][0]=0.f;acc[p][1]=0.f;acc[p][2]=0.f;}
  for (int e = 0; e < E; e += 4) {
    float w0_[4], w1_[4], w2_[4];
    #pragma unroll
    for (int i=0;i<4;i++){
      w0_[i]=wT[(e+i)*G3 + g];
      w1_[i]=wT[(e+i)*G3 + 256 + g];
      w2_[i]=wT[(e+i)*G3 + 512 + g];
    }
    #pragma unroll
    for (int p=0;p<16;p++){
      float4 ev = *(const float4*)&emb_s[p][e];
      acc[p][0] += ev.x*w0_[0]+ev.y*w0_[1]+ev.z*w0_[2]+ev.w*w0_[3];
      acc[p][1] += ev.x*w1_[0]+ev.y*w1_[1]+ev.z*w1_[2]+ev.w*w1_[3];
      acc[p][2] += ev.x*w2_[0]+ev.y*w2_[1]+ev.z*w2_[2]+ev.w*w2_[3];
    }
  }
  #pragma unroll
  for (int p=0;p<16;p++){
    int r = r0+p; int tt = tm_s[p];
    xp0[(size_t)r*G3 + g]       = acc[p][0] + b_ih0[g]     + w_ih0[g*DIN       + E + tt];
    xp0[(size_t)r*G3 + 256 + g] = acc[p][1] + b_ih0[g+256] + w_ih0[(g+256)*DIN + E + tt];
    xp0[(size_t)r*G3 + 512 + g] = acc[p][2] + b_ih0[g+512] + w_ih0[(g+512)*DIN + E + tt];
  }
}

// ---------------- K2: cooperative 2-layer GRU, MFMA recurrence, weights in VGPRs -----
// 16 blocks (one per 16-wide j-tile) x 384 threads (6 waves = 2 m-tiles x 3 gates).
// L0 processes step t=p while L1 processes t=p-1 (x for L1 == y0 == h0 stream).
struct GruArgs {
  const float* xp0; const float* traj; const int* labels;
  const float* w_hh0; const float* b_hh0;
  const float* w_ih1; const float* w_hh1; const float* b_ih1; const float* b_hh1;
  float* h0f; float* h1f;                 // [2][32*256] fp32 carry state
  unsigned short* h0bf; unsigned short* h1bf;  // [2][32*256] bf16 matmul inputs
  unsigned short* abf;                    // [(b*48+t)*256 + j] relu-bf16 FC input
};

__global__ void __launch_bounds__(384, 2) gru_kernel(GruArgs a)
{
  __shared__ unsigned short A0[32*264];   // h0/y0 bf16, row stride 264 (pad 8)
  __shared__ unsigned short A1[32*264];   // h1 bf16
  __shared__ float gl0[3*32*17];          // L0 gate pre-acts (hr,hz,hn)
  __shared__ float gl1[4*32*17];          // L1 gate pre-acts (r,z,nx,nh)
  cg::grid_group grid = cg::this_grid();
  const int tid  = threadIdx.x;
  const int jt   = blockIdx.x;            // j-tile [jt*16, jt*16+16)
  const int wv   = tid >> 6;              // 0..5
  const int lane = tid & 63;
  const int g    = wv % 3, mt = wv / 3;   // gate, m-tile
  const int fn   = lane & 15;             // fragment n (out row) / m (batch)
  const int fq   = lane >> 4;             // quad -> k offset fq*8

  // ---- B fragments (weights) loaded ONCE into registers ----
  // b0[kk]: w_hh0 row (g*256 + jt*16 + fn), k = kk*32 + fq*8 .. +8
  // b1[0..7]: w_ih1 same row; b1[8..15]: w_hh1 same row
  const int row = g*256 + jt*16 + fn;
  s16x8 b0[8], b1[16];
  #pragma unroll
  for (int kk = 0; kk < 8; ++kk) {
    const float* p0 = a.w_hh0 + (size_t)row*H + kk*32 + fq*8;
    const float* p1 = a.w_ih1 + (size_t)row*H + kk*32 + fq*8;
    const float* p2 = a.w_hh1 + (size_t)row*H + kk*32 + fq*8;
    b0[kk]    = pack8(*(const float4*)p0, *(const float4*)(p0+4));
    b1[kk]    = pack8(*(const float4*)p1, *(const float4*)(p1+4));
    b1[kk+8]  = pack8(*(const float4*)p2, *(const float4*)(p2+4));
  }

  // ---- init hidden from traj table (torch reshape(2,32,256) view) ----
  // L0 first used at phase 0 (parity 0); L1 first used at phase 1 (parity 1).
  for (int i = blockIdx.x*384 + tid; i < 2*B*H; i += 16*384) {
    int l = i >> 13, bb = (i >> 8) & 31, h = i & 255;
    float v = a.traj[(size_t)a.labels[l*16 + (bb>>1)]*512 + (bb&1)*256 + h];
    if (l == 0) { a.h0f[bb*256+h] = v;        a.h0bf[bb*256+h] = f2bf(v); }
    else        { a.h1f[8192+bb*256+h] = v;   a.h1bf[8192+bb*256+h] = f2bf(v); }
  }
  grid.sync();

  for (int p = 0; p <= T; ++p) {
    const int cur = p & 1, nxt = cur ^ 1;
    // ---- stage h0/y0 and h1 (bf16) into LDS ----
    {
      const unsigned short* s0 = a.h0bf + cur*8192;
      const unsigned short* s1 = a.h1bf + cur*8192;
      for (int i = tid; i < 1024; i += 384) {
        int b = i >> 5, kg = (i & 31) * 8;
        *(uint4*)&A0[b*264 + kg] = *(const uint4*)&s0[b*256 + kg];
        *(uint4*)&A1[b*264 + kg] = *(const uint4*)&s1[b*256 + kg];
      }
    }
    __syncthreads();

    // ---- MFMA phase ----
    if (p < T) {            // L0, t = p: gates_h = h0 @ w_hh0^T
      f32x4 acc = (f32x4){0.f,0.f,0.f,0.f};
      #pragma unroll
      for (int kk = 0; kk < 8; ++kk) {
        s16x8 af = *(const s16x8*)&A0[(mt*16 + fn)*264 + kk*32 + fq*8];
        acc = __builtin_amdgcn_mfma_f32_16x16x32_bf16(af, b0[kk], acc, 0, 0, 0);
      }
      #pragma unroll
      for (int i = 0; i < 4; ++i)
        gl0[(g*32 + mt*16 + fq*4 + i)*17 + fn] = acc[i];
    }
    if (p >= 1) {           // L1, t = p-1: x = y0 (A0), h = h1 (A1)
      if (g < 2) {          // r,z: concat-K is valid
        f32x4 acc = (f32x4){0.f,0.f,0.f,0.f};
        #pragma unroll
        for (int kk = 0; kk < 8; ++kk) {
          s16x8 af = *(const s16x8*)&A0[(mt*16 + fn)*264 + kk*32 + fq*8];
          acc = __builtin_amdgcn_mfma_f32_16x16x32_bf16(af, b1[kk], acc, 0, 0, 0);
        }
        #pragma unroll
        for (int kk = 0; kk < 8; ++kk) {
          s16x8 af = *(const s16x8*)&A1[(mt*16 + fn)*264 + kk*32 + fq*8];
          acc = __builtin_amdgcn_mfma_f32_16x16x32_bf16(af, b1[8+kk], acc, 0, 0, 0);
        }
        #pragma unroll
        for (int i = 0; i < 4; ++i)
          gl1[(g*32 + mt*16 + fq*4 + i)*17 + fn] = acc[i];
      } else {              // n: x-part and h-part must stay separate (r * h-part)
        f32x4 ax = (f32x4){0.f,0.f,0.f,0.f}, ah = (f32x4){0.f,0.f,0.f,0.f};
        #pragma unroll
        for (int kk = 0; kk < 8; ++kk) {
          s16x8 afx = *(const s16x8*)&A0[(mt*16 + fn)*264 + kk*32 + fq*8];
          s16x8 afh = *(const s16x8*)&A1[(mt*16 + fn)*264 + kk*32 + fq*8];
          ax = __builtin_amdgcn_mfma_f32_16x16x32_bf16(afx, b1[kk],   ax, 0, 0, 0);
          ah = __builtin_amdgcn_mfma_f32_16x16x32_bf16(afh, b1[8+kk], ah, 0, 0, 0);
        }
        #pragma unroll
        for (int i = 0; i < 4; ++i) {
          gl1[(2*32 + mt*16 + fq*4 + i)*17 + fn] = ax[i];
          gl1[(3*32 + mt*16 + fq*4 + i)*17 + fn] = ah[i];
        }
      }
    }
    __syncthreads();

    // ---- pointwise update (fp32 carry) ----
    if (p < T) {
      for (int s = tid; s < 512; s += 384) {
        int b = s >> 4, j = s & 15, gj = jt*16 + j;
        float hr = gl0[(b)*17+j], hz = gl0[(32+b)*17+j], hn = gl0[(64+b)*17+j];
        const float* xp = a.xp0 + (size_t)(p*B + b)*G3 + gj;
        float xr = xp[0], xz = xp[256], xn = xp[512];
        float r = sigmoidf_(xr + hr + a.b_hh0[gj]);
        float z = sigmoidf_(xz + hz + a.b_hh0[256+gj]);
        float n = tanhf_(xn + r*(hn + a.b_hh0[512+gj]));
        float hp = a.h0f[cur*8192 + b*256 + gj];
        float hnew = (1.f - z)*n + z*hp;
        a.h0f [nxt*8192 + b*256 + gj] = hnew;
        a.h0bf[nxt*8192 + b*256 + gj] = f2bf(hnew);
      }
    }
    if (p >= 1) {
      const int t1 = p - 1;
      for (int s = tid; s < 512; s += 384) {
        int b = s >> 4, j = s & 15, gj = jt*16 + j;
        float gr = gl1[(b)*17+j],    gz = gl1[(32+b)*17+j];
        float nx = gl1[(64+b)*17+j], nh = gl1[(96+b)*17+j];
        float r = sigmoidf_(gr + a.b_ih1[gj]     + a.b_hh1[gj]);
        float z = sigmoidf_(gz + a.b_ih1[256+gj] + a.b_hh1[256+gj]);
        float n = tanhf_(nx + a.b_ih1[512+gj] + r*(nh + a.b_hh1[512+gj]));
        float hp = a.h1f[cur*8192 + b*256 + gj];
        float hnew = (1.f - z)*n + z*hp;
        a.h1f [nxt*8192 + b*256 + gj] = hnew;
        a.h1bf[nxt*8192 + b*256 + gj] = f2bf(hnew);
        a.abf[(size_t)(b*T + t1)*H + gj] = f2bf(fmaxf(hnew, 0.f));  // relu, FC layout
      }
    }
    grid.sync();
  }
}

// ---------------- cast fc_w to bf16 (pad cols to 40064 with zero rows) ---------------
__global__ void castw_kernel(const float* __restrict__ fcw, unsigned short* __restrict__ wbf){
  int g = blockIdx.x*256 + threadIdx.x;   // float4 groups, NPADC*64 total
  if (g >= NPADC*64) return;
  int row = g >> 6;
  ushort4 o;
  if (row < NOUTC) {
    float4 v = ((const float4*)fcw)[g];
    o.x=f2bf(v.x); o.y=f2bf(v.y); o.z=f2bf(v.z); o.w=f2bf(v.w);
  } else { o.x=0; o.y=0; o.z=0; o.w=0; }
  ((ushort4*)wbf)[g] = o;
}

// ---------------- K4: bf16 MFMA GEMM  C[1536 x 40048] = A·W^T + b -> raw logits ------
__global__ void __launch_bounds__(256) gemm_kernel(const unsigned short* __restrict__ Abf,
                                                   const unsigned short* __restrict__ Wbf,
                                                   const float* __restrict__ fc_b,
                                                   float* __restrict__ dout)
{
  __shared__ unsigned short As[128*32];
  __shared__ unsigned short Ws[128*32];
  const int m0 = blockIdx.x * 128;
  const int n0 = blockIdx.y * 128;
  const int tid = threadIdx.x;
  const int lane = tid & 63;
  const int wv = tid >> 6;
  f32x4 acc[2][8];
  #pragma unroll
  for (int i=0;i<2;i++)
    #pragma unroll
    for(int jx=0;jx<8;jx++) acc[i][jx] = (f32x4){0.f,0.f,0.f,0.f};

  const int srow = tid >> 2;
  const int skoff = (tid & 3) * 8;
  const unsigned short* aptr = Abf + (size_t)(m0 + srow)*256 + skoff;
  const unsigned short* wptr = Wbf + (size_t)(n0 + srow)*256 + skoff;
  unsigned short* asd = &As[tid*8];
  unsigned short* wsd = &Ws[tid*8];

  const int fr = lane & 15;
  const int fk = (lane >> 4) * 8;

  for (int kk = 0; kk < 256; kk += 32) {
    gl_lds16(aptr + kk,            asd);
    gl_lds16(aptr + 64*256 + kk,   asd + 64*32);
    gl_lds16(wptr + kk,            wsd);
    gl_lds16(wptr + 64*256 + kk,   wsd + 64*32);
    __syncthreads();
    s16x8 a0 = *(const s16x8*)&As[(wv*32 + fr)*32 + fk];
    s16x8 a1 = *(const s16x8*)&As[(wv*32 + 16 + fr)*32 + fk];
    #pragma unroll
    for (int ct = 0; ct < 8; ++ct) {
      s16x8 bfr = *(const s16x8*)&Ws[(ct*16 + fr)*32 + fk];
      acc[0][ct] = __builtin_amdgcn_mfma_f32_16x16x32_bf16(a0, bfr, acc[0][ct], 0, 0, 0);
      acc[1][ct] = __builtin_amdgcn_mfma_f32_16x16x32_bf16(a1, bfr, acc[1][ct], 0, 0, 0);
    }
    __syncthreads();
  }

  const int quad = lane >> 4;
  #pragma unroll
  for (int rt = 0; rt < 2; ++rt) {
    #pragma unroll
    for (int ct = 0; ct < 8; ++ct) {
      int col = n0 + ct*16 + fr;
      if (col < NOUTC) {
        float bias = fc_b[col];
        #pragma unroll
        for (int i = 0; i < 4; ++i) {
          int row = m0 + wv*32 + rt*16 + quad*4 + i;
          float v = acc[rt][ct][i] + bias;
          if (col < OUT) dout[(size_t)row*OUT + col] = v;
          else dout[(size_t)OUT*B*T + (size_t)row*TD + (col - OUT)] = v;
        }
      }
    }
  }
}

// ---------------- K5: per-row online logsumexp over the 40000 loc logits -------------
__global__ void stats_kernel(const float* __restrict__ dout, float* __restrict__ logz){
  const int r = blockIdx.x;
  const float4* row = (const float4*)(dout + (size_t)r*OUT);
  float m = -INFINITY, s = 0.f;
  for (int i = threadIdx.x; i < OUT/4; i += 256) {
    float4 v = row[i];
    float mx = fmaxf(fmaxf(v.x,v.y), fmaxf(v.z,v.w));
    if (mx > m) { s *= __expf(m - mx); m = mx; }
    s += __expf(v.x-m)+__expf(v.y-m)+__expf(v.z-m)+__expf(v.w-m);
  }
  #pragma unroll
  for (int off = 1; off < 64; off <<= 1) {
    float m2 = __shfl_xor(m, off);
    float s2 = __shfl_xor(s, off);
    float nm = fmaxf(m, m2);
    s = s*__expf(m-nm) + s2*__expf(m2-nm);
    m = nm;
  }
  __shared__ float sm[4], ss[4];
  if ((threadIdx.x & 63) == 0){ sm[threadIdx.x>>6]=m; ss[threadIdx.x>>6]=s; }
  __syncthreads();
  if (threadIdx.x == 0){
    float M=sm[0], S=ss[0];
    #pragma unroll
    for (int w=1;w<4;w++){
      float nm=fmaxf(M,sm[w]); S = S*__expf(M-nm)+ss[w]*__expf(sm[w]-nm); M=nm;
    }
    logz[r] = M + logf(S);
  }
}

// ---------------- K6: in-place normalize loc ----------------------------------------
__global__ void norm_kernel(float* __restrict__ dout, const float* __restrict__ logz){
  size_t i = (size_t)blockIdx.x*256 + threadIdx.x;   // float4 index
  if (i >= (size_t)B*T*OUT/4) return;
  int r = (int)(i / (OUT/4));
  float lz = logz[r];
  float4* p = (float4*)dout + i;
  float4 v = *p;
  v.x -= lz; v.y -= lz; v.z -= lz; v.w -= lz;
  *p = v;
}

// ---------------- K7: tm log_softmax (48 wide), in place -----------------------------
__global__ void tm_kernel(float* __restrict__ dout){
  const int r = blockIdx.x;
  const int lane = threadIdx.x;   // 64
  float* base = dout + (size_t)OUT*B*T + (size_t)r*TD;
  float v = (lane < TD) ? base[lane] : -INFINITY;
  float m = v;
  #pragma unroll
  for (int off=32; off; off>>=1) m = fmaxf(m, __shfl_xor(m, off));
  float e = (lane < TD) ? __expf(v - m) : 0.f;
  float s = e;
  #pragma unroll
  for (int off=32; off; off>>=1) s += __shfl_xor(s, off);
  float lz = m + logf(s);
  if (lane < TD) base[lane] = v - lz;
}

extern "C" void kernel_launch(void* const* d_in, const int* in_sizes, int n_in,
                              void* d_out, int out_size, void* d_ws, size_t ws_size,
                              hipStream_t stream)
{
  const int*   locations = (const int*)d_in[0];
  const int*   times     = (const int*)d_in[1];
  const int*   labels    = (const int*)d_in[2];
  const float* embed     = (const float*)d_in[3];
  const float* traj      = (const float*)d_in[4];
  const float* fc_w      = (const float*)d_in[5];
  const float* fc_b      = (const float*)d_in[6];
  const float* w_ih0     = (const float*)d_in[7];
  const float* w_hh0     = (const float*)d_in[8];
  const float* b_ih0     = (const float*)d_in[9];
  const float* b_hh0     = (const float*)d_in[10];
  const float* w_ih1     = (const float*)d_in[11];
  const float* w_hh1     = (const float*)d_in[12];
  const float* b_ih1     = (const float*)d_in[13];
  const float* b_hh1     = (const float*)d_in[14];
  float* out = (float*)d_out;
  char* ws = (char*)d_ws;

  float* xp0            = (float*)(ws);                    // 4,718,592 B
  float* h0f            = (float*)(ws + 4718592);          //    65,536
  float* h1f            = (float*)(ws + 4784128);          //    65,536
  unsigned short* h0bf  = (unsigned short*)(ws + 4849664); //    32,768
  unsigned short* h1bf  = (unsigned short*)(ws + 4882432); //    32,768
  float* logz           = (float*)(ws + 4915200);          //     6,144
  unsigned short* abf   = (unsigned short*)(ws + 4921344); //   786,432
  unsigned short* wbf   = (unsigned short*)(ws + 5707776); // 20,512,768
  float* wT             = (float*)(ws + 26220544);         //   393,216 -> ~26.6 MB

  castw_kernel<<<dim3((NPADC*64 + 255)/256), dim3(256), 0, stream>>>(fc_w, wbf);
  wt_kernel<<<dim3((E*G3 + 255)/256), dim3(256), 0, stream>>>(w_ih0, wT);
  xp0_kernel<<<dim3(96), dim3(256), 0, stream>>>(locations, times, embed, wT, w_ih0, b_ih0, xp0);

  GruArgs ga{xp0, traj, labels, w_hh0, b_hh0, w_ih1, w_hh1, b_ih1, b_hh1,
             h0f, h1f, h0bf, h1bf, abf};
  void* kargs[] = { &ga };
  hipLaunchCooperativeKernel((void*)gru_kernel, dim3(16), dim3(384), kargs, 0, stream);

  gemm_kernel<<<dim3(12, 313), dim3(256), 0, stream>>>(abf, wbf, fc_b, out);
  stats_kernel<<<dim3(B*T), dim3(256), 0, stream>>>(out, logz);
  norm_kernel<<<dim3((B*T*OUT/4 + 255)/256), dim3(256), 0, stream>>>(out, logz);
  tm_kernel<<<dim3(B*T), dim3(64), 0, stream>>>(out);
}